// Round 2
// baseline (318.622 us; speedup 1.0000x reference)
//
#include <hip/hip_runtime.h>
#include <stdint.h>

#define M_DIM 32768
#define K_DIM 1024
#define N_DIM 1024

typedef int v4i __attribute__((ext_vector_type(4)));

// ---------------- async global->LDS helper (16B wide) ----------------
__device__ __forceinline__ void gld_lds16(const void* g, void* lds) {
    __builtin_amdgcn_global_load_lds(
        (const __attribute__((address_space(1))) unsigned int*)g,
        (__attribute__((address_space(3))) unsigned int*)lds, 16, 0, 0);
}

// ---------------- kernel 1: partial min/max ----------------
__global__ void k_minmax(const float* __restrict__ x,
                         float* __restrict__ pmin, float* __restrict__ pmax) {
    int t = threadIdx.x;
    long gid = (long)blockIdx.x * blockDim.x + t;
    const float4* x4 = (const float4*)x;
    const long n4 = (long)M_DIM * K_DIM / 4;
    float mn = INFINITY, mx = -INFINITY;
    for (long i = gid; i < n4; i += (long)gridDim.x * blockDim.x) {
        float4 v = x4[i];
        mn = fminf(mn, fminf(fminf(v.x, v.y), fminf(v.z, v.w)));
        mx = fmaxf(mx, fmaxf(fmaxf(v.x, v.y), fmaxf(v.z, v.w)));
    }
    __shared__ float smn[256], smx[256];
    smn[t] = mn; smx[t] = mx;
    __syncthreads();
    for (int s = 128; s > 0; s >>= 1) {
        if (t < s) {
            smn[t] = fminf(smn[t], smn[t + s]);
            smx[t] = fmaxf(smx[t], smx[t + s]);
        }
        __syncthreads();
    }
    if (t == 0) { pmin[blockIdx.x] = smn[0]; pmax[blockIdx.x] = smx[0]; }
}

// ---------------- kernel 2: finalize scale / zero-point ----------------
__global__ void k_finalize(const float* __restrict__ pmin,
                           const float* __restrict__ pmax,
                           float* __restrict__ sp) {
    int t = threadIdx.x;
    float mn = INFINITY, mx = -INFINITY;
    for (int i = t; i < 1024; i += 256) {
        mn = fminf(mn, pmin[i]);
        mx = fmaxf(mx, pmax[i]);
    }
    __shared__ float smn[256], smx[256];
    smn[t] = mn; smx[t] = mx;
    __syncthreads();
    for (int s = 128; s > 0; s >>= 1) {
        if (t < s) {
            smn[t] = fminf(smn[t], smn[t + s]);
            smx[t] = fmaxf(smx[t], smx[t + s]);
        }
        __syncthreads();
    }
    if (t == 0) {
        float min_neg = fminf(smn[0], 0.0f);
        float max_pos = fmaxf(smx[0], 0.0f);
        float scale = (max_pos - min_neg) / 255.0f;      // IEEE div, matches jnp
        scale = fmaxf(scale, 1.1920928955078125e-07f);   // np.finfo(f32).eps
        float zp = -128.0f - rintf(min_neg / scale);     // rintf = RTNE = jnp.round
        zp = fminf(fmaxf(zp, -128.0f), 127.0f);
        sp[0] = scale;
        sp[1] = zp;
    }
}

// ---------------- kernel 3: quantize x -> int8 ----------------
__device__ __forceinline__ unsigned q4(float4 v, float s, float zp) {
    int a = (int)fminf(fmaxf(rintf(v.x / s) + zp, -128.0f), 127.0f);
    int b = (int)fminf(fmaxf(rintf(v.y / s) + zp, -128.0f), 127.0f);
    int c = (int)fminf(fmaxf(rintf(v.z / s) + zp, -128.0f), 127.0f);
    int d = (int)fminf(fmaxf(rintf(v.w / s) + zp, -128.0f), 127.0f);
    return (a & 255) | ((b & 255) << 8) | ((c & 255) << 16) | ((d & 255) << 24);
}

__global__ void k_quant(const float* __restrict__ x,
                        const float* __restrict__ sp,
                        int8_t* __restrict__ xq) {
    float s = sp[0], zp = sp[1];
    long g = (long)blockIdx.x * blockDim.x + threadIdx.x;  // 0 .. 2M-1
    const float4* x4 = (const float4*)x + g * 4;
    float4 v0 = x4[0], v1 = x4[1], v2 = x4[2], v3 = x4[3];
    uint4 r;
    r.x = q4(v0, s, zp);
    r.y = q4(v1, s, zp);
    r.z = q4(v2, s, zp);
    r.w = q4(v3, s, zp);
    ((uint4*)xq)[g] = r;
}

// ---------------- kernel 4: transpose w [K,N] int32 -> wt [N,K] int8 ----------------
// NOTE: harness delivers integer inputs widened to int32 — w_int8_t arrives as
// const int* (4 B/elem). Narrow to int8 here.
__global__ void k_transpose(const int* __restrict__ w, int8_t* __restrict__ wt) {
    __shared__ int8_t tile[32][33];
    int bn = blockIdx.x * 32;
    int bk = blockIdx.y * 32;
    int tx = threadIdx.x, ty = threadIdx.y;
#pragma unroll
    for (int i = 0; i < 32; i += 8)
        tile[ty + i][tx] = (int8_t)w[(long)(bk + ty + i) * N_DIM + bn + tx];
    __syncthreads();
#pragma unroll
    for (int i = 0; i < 32; i += 8)
        wt[(long)(bn + ty + i) * K_DIM + bk + tx] = tile[tx][ty + i];
}

// ---------------- kernel 5: int8 GEMM + dequant + bias ----------------
// 128x128 tile per block (4 waves, each 64x64 via 4x4 MFMA 16x16x64 tiles), BK=64.
// LDS layout: [row][64 bytes] with XOR swizzle on 16B quads:
//   slot s in row m holds global quad q = s ^ (m&3) ^ ((m>>2)&3)
// -> ds_read_b128 of any quad hits all 32 banks across 8 consecutive rows (2-way, free).
__global__ __launch_bounds__(256) void k_gemm(
    const int8_t* __restrict__ xq, const int8_t* __restrict__ wt,
    const float* __restrict__ sp, const float* __restrict__ w_scales,
    const int* __restrict__ wsums, const float* __restrict__ bias,
    float* __restrict__ out) {
    __shared__ __align__(16) int8_t lds_a[128 * 64];
    __shared__ __align__(16) int8_t lds_b[128 * 64];

    const int t = threadIdx.x;
    const int m0 = blockIdx.y * 128;
    const int n0 = blockIdx.x * 128;
    const int w = t >> 6, l = t & 63, quad = l >> 4, r = l & 15;
    const int wave_m = (w & 1) * 64, wave_n = (w >> 1) * 64;

    v4i acc[4][4];
#pragma unroll
    for (int i = 0; i < 4; i++)
#pragma unroll
        for (int j = 0; j < 4; j++) acc[i][j] = (v4i){0, 0, 0, 0};

    // staging: 2 slots per thread per operand; slot -> (row, swizzled global quad)
    const int slot0 = t, slot1 = 256 + t;
    const int row0 = slot0 >> 2, s0 = slot0 & 3;
    const int row1 = slot1 >> 2, s1 = slot1 & 3;
    const int q0 = s0 ^ (row0 & 3) ^ ((row0 >> 2) & 3);
    const int q1 = s1 ^ (row1 & 3) ^ ((row1 >> 2) & 3);
    const int8_t* gA0 = xq + (long)(m0 + row0) * K_DIM + q0 * 16;
    const int8_t* gA1 = xq + (long)(m0 + row1) * K_DIM + q1 * 16;
    const int8_t* gB0 = wt + (long)(n0 + row0) * K_DIM + q0 * 16;
    const int8_t* gB1 = wt + (long)(n0 + row1) * K_DIM + q1 * 16;

    // LDS read addresses (per-lane fragment reads, swizzle-corrected)
    int ra[4], rb[4];
#pragma unroll
    for (int i = 0; i < 4; i++) {
        int mrow = wave_m + i * 16 + r;
        int sa = quad ^ (mrow & 3) ^ ((mrow >> 2) & 3);
        ra[i] = mrow * 64 + sa * 16;
        int nrow = wave_n + i * 16 + r;
        int sb = quad ^ (nrow & 3) ^ ((nrow >> 2) & 3);
        rb[i] = nrow * 64 + sb * 16;
    }

    for (int kb = 0; kb < K_DIM; kb += 64) {
        gld_lds16(gA0 + kb, lds_a + slot0 * 16);
        gld_lds16(gA1 + kb, lds_a + slot1 * 16);
        gld_lds16(gB0 + kb, lds_b + slot0 * 16);
        gld_lds16(gB1 + kb, lds_b + slot1 * 16);
        __syncthreads();

        v4i af[4], bf[4];
#pragma unroll
        for (int i = 0; i < 4; i++) af[i] = *(const v4i*)(lds_a + ra[i]);
#pragma unroll
        for (int j = 0; j < 4; j++) bf[j] = *(const v4i*)(lds_b + rb[j]);
#pragma unroll
        for (int i = 0; i < 4; i++)
#pragma unroll
            for (int j = 0; j < 4; j++)
                acc[i][j] = __builtin_amdgcn_mfma_i32_16x16x64_i8(af[i], bf[j], acc[i][j], 0, 0, 0);
        __syncthreads();
    }

    // epilogue: y = x_scale * w_scales[n] * (acc - x_zp * wsum[n]) + bias[n]
    const float scale = sp[0], zp = sp[1];
#pragma unroll
    for (int j = 0; j < 4; j++) {
        int n = n0 + wave_n + j * 16 + r;
        float sj = scale * w_scales[n];
        float cj = zp * (float)wsums[n];
        float bj = bias[n];
#pragma unroll
        for (int i = 0; i < 4; i++) {
            int mbase = m0 + wave_m + i * 16 + quad * 4;
#pragma unroll
            for (int e = 0; e < 4; e++) {
                out[(long)(mbase + e) * N_DIM + n] = sj * ((float)acc[i][j][e] - cj) + bj;
            }
        }
    }
}

// ---------------- launcher ----------------
extern "C" void kernel_launch(void* const* d_in, const int* in_sizes, int n_in,
                              void* d_out, int out_size, void* d_ws, size_t ws_size,
                              hipStream_t stream) {
    const float* x        = (const float*)d_in[0];
    const int*   w_int8_t = (const int*)d_in[1];   // int8 values widened to int32 by harness
    const float* w_scales = (const float*)d_in[2];
    const int*   w_sums   = (const int*)d_in[3];
    const float* bias     = (const float*)d_in[4];
    float* out = (float*)d_out;

    // ws layout: [0..1023] pmin, [1024..2047] pmax, [2048..2049] (scale,zp),
    // byte 16384: wt (1 MB), byte 16384+1MB: xq (32 MB)
    float* wsf  = (float*)d_ws;
    float* pmin = wsf;
    float* pmax = wsf + 1024;
    float* sp   = wsf + 2048;
    int8_t* wt  = (int8_t*)d_ws + 16384;
    int8_t* xq  = (int8_t*)d_ws + 16384 + (size_t)K_DIM * N_DIM;

    k_minmax<<<1024, 256, 0, stream>>>(x, pmin, pmax);
    k_finalize<<<1, 256, 0, stream>>>(pmin, pmax, sp);
    k_quant<<<8192, 256, 0, stream>>>(x, sp, xq);
    k_transpose<<<dim3(N_DIM / 32, K_DIM / 32), dim3(32, 8), 0, stream>>>(w_int8_t, wt);
    k_gemm<<<dim3(N_DIM / 128, M_DIM / 128), 256, 0, stream>>>(
        xq, wt, sp, w_scales, w_sums, bias, out);
}